// Round 3
// baseline (4161.061 us; speedup 1.0000x reference)
//
#include <hip/hip_runtime.h>
#include <hip/hip_bf16.h>

typedef _Float16 f16;
typedef _Float16 f16x8 __attribute__((ext_vector_type(8)));
typedef float f32x4 __attribute__((ext_vector_type(4)));

#define B_ 128
#define T_ 256
#define D_ 1280
#define G3_ 3840
#define C_ 100
#define TB_ 32768  /* T_*B_ */

// ---- workspace layout (bytes) ----
#define O_SEQB 0ull                 // f16 [TB_][D_]   (row = t*128+b)
#define O_WIH  83886080ull          // f16 [G3_][D_]
#define O_WHH  93716480ull          // f16 [G3_][D_]
#define O_XP   103546880ull         // f16 [T_][80][3][128][16] compact slabs
#define O_H16  355205120ull         // f16 [2][B_][D_]
#define O_H32  355860480ull         // f32 [B_][D_]
#define O_BAR  356515840ull         // unsigned counters (2 rowgroups, 64B apart)

// ---------------- conversion / init ----------------
__global__ void k_convert(const float* __restrict__ seq, const float* __restrict__ wih,
                          const float* __restrict__ whh, f16* __restrict__ seqb,
                          f16* __restrict__ wih16, f16* __restrict__ whh16,
                          unsigned* __restrict__ bar) {
  if (blockIdx.x == 0 && threadIdx.x < 32) bar[threadIdx.x] = 0u;
  const long NSEQ = (long)TB_ * (D_ / 8);
  const long NW = (long)G3_ * (D_ / 8);
  const long total = NSEQ + 2 * NW;
  for (long i = (long)blockIdx.x * blockDim.x + threadIdx.x; i < total;
       i += (long)gridDim.x * blockDim.x) {
    const float* src;
    f16* dst;
    if (i < NSEQ) {
      long row = i / (D_ / 8), c = i % (D_ / 8);
      long t = row >> 7, b = row & 127;
      src = seq + ((b * T_ + t) * (long)D_ + c * 8);
      dst = seqb + (row * (long)D_ + c * 8);
    } else if (i < NSEQ + NW) {
      long j = i - NSEQ;
      src = wih + j * 8;
      dst = wih16 + j * 8;
    } else {
      long j = i - NSEQ - NW;
      src = whh + j * 8;
      dst = whh16 + j * 8;
    }
    float4 a = *(const float4*)src, b4 = *(const float4*)(src + 4);
    f16x8 o;
    o[0] = (f16)a.x; o[1] = (f16)a.y; o[2] = (f16)a.z; o[3] = (f16)a.w;
    o[4] = (f16)b4.x; o[5] = (f16)b4.y; o[6] = (f16)b4.z; o[7] = (f16)b4.w;
    *(f16x8*)dst = o;
  }
}

// ---------------- x_proj GEMM -> compact slab layout [t][cg][g][b][c16] ----------------
__device__ __forceinline__ void gl_lds16(const f16* g, f16* lds) {
  __builtin_amdgcn_global_load_lds((const __attribute__((address_space(1))) void*)g,
                                   (__attribute__((address_space(3))) void*)lds, 16, 0, 0);
}

__global__ __launch_bounds__(256) void k_xproj(const f16* __restrict__ A, const f16* __restrict__ Bw,
                                               const float* __restrict__ bih, f16* __restrict__ Cout) {
  __shared__ f16 Alds[128 * 32];
  __shared__ f16 Blds[128 * 32];
  int bid = blockIdx.x;
  // superblock swizzle: 8 bm-tiles x 30 bn-tiles per superblock (keeps W_ih hot)
  int sb = bid / 240;
  int wi = bid % 240;
  int bm = sb * 8 + (wi & 7);
  int bn = wi >> 3;
  long brow = (long)bm * 128;
  int bcol = bn * 128;
  int tid = threadIdx.x, w = tid >> 6, l = tid & 63;
  int wm = w & 1, wn = w >> 1;

  f32x4 acc[4][4] = {};

  int sr = w * 32 + (l >> 2);   // staging row (first instr), +16 for second
  int sc = (l & 3) * 8;         // k-elem offset (16B chunk)
  const f16* gA = A + (brow + sr) * (long)D_ + sc;
  const f16* gB = Bw + (long)(bcol + sr) * D_ + sc;
  f16* lAw = Alds + (w * 32) * 32;  // wave-uniform LDS dest base
  f16* lBw = Blds + (w * 32) * 32;

  int fr = l & 15, fc = (l >> 4) * 8;

  for (int kb = 0; kb < 40; ++kb) {
    const f16* a0 = gA + kb * 32;
    const f16* b0 = gB + kb * 32;
    gl_lds16(a0, lAw);
    gl_lds16(a0 + 16 * D_, lAw + 16 * 32);
    gl_lds16(b0, lBw);
    gl_lds16(b0 + 16 * D_, lBw + 16 * 32);
    __syncthreads();
    f16x8 af[4], bf[4];
#pragma unroll
    for (int mt = 0; mt < 4; ++mt) af[mt] = *(const f16x8*)(Alds + (wm * 64 + mt * 16 + fr) * 32 + fc);
#pragma unroll
    for (int nt = 0; nt < 4; ++nt) bf[nt] = *(const f16x8*)(Blds + (wn * 64 + nt * 16 + fr) * 32 + fc);
#pragma unroll
    for (int mt = 0; mt < 4; ++mt)
#pragma unroll
      for (int nt = 0; nt < 4; ++nt)
        acc[mt][nt] = __builtin_amdgcn_mfma_f32_16x16x32_f16(af[mt], bf[nt], acc[mt][nt], 0, 0, 0);
    __syncthreads();
  }
  // epilogue: add b_ih, store f16 into compact slab layout.
  // t = bm (tile covers rows bm*128..bm*128+127 exactly).
#pragma unroll
  for (int nt = 0; nt < 4; ++nt) {
    int col = bcol + wn * 64 + nt * 16 + fr;   // 0..3839; gate/cg uniform within 16-col group
    int g = col / D_;
    int dcol = col - g * D_;
    int cg = dcol >> 4, c16 = dcol & 15;
    float bv = bih[col];
    f16* base = Cout + (((long)bm * 80 + cg) * 3 + g) * 2048 + c16;
#pragma unroll
    for (int mt = 0; mt < 4; ++mt) {
#pragma unroll
      for (int i = 0; i < 4; ++i) {
        int b = wm * 64 + mt * 16 + (l >> 4) * 4 + i;
        base[b * 16] = (f16)(acc[mt][nt][i] + bv);
      }
    }
  }
}

// ---------------- GRU scan: persistent, 160 blocks (2 rowgrp x 80 colgrp) ----------------
// h traffic: plain cached loads/stores; coherence via one wbl2 (release fence) before
// the barrier arrival and one buffer_inv (acquire fence) after the poll — per block per step.
__global__ __launch_bounds__(256, 1) void k_scan(const f16* __restrict__ whh16,
                                                 const f16* __restrict__ xproj,
                                                 const float* __restrict__ bhh,
                                                 f16* __restrict__ h16, float* __restrict__ h32,
                                                 unsigned* __restrict__ bar) {
  __shared__ f16 wlds[3 * 16 * D_];  // 120 KB, XOR-swizzled 16B chunks
  int wg = blockIdx.x;
  int rg = wg / 80, cg = wg % 80;
  int r0 = rg * 64, d0 = cg * 16;
  int tid = threadIdx.x, w = tid >> 6, l = tid & 63;
  int wr0 = r0 + w * 16;
  int fr = l & 15, fq = l >> 4;
  int mycol = d0 + fr;
  unsigned* cnt = bar + rg * 16;  // per-rowgroup counter, own cacheline

  // load W_hh chunk into LDS (once, lives for all 256 steps)
  for (int q = tid; q < 3 * 16 * (D_ / 8); q += 256) {
    int gj = q / 160, c = q % 160;
    int j = gj & 15, g = gj >> 4;
    uint4 v = *(const uint4*)(whh16 + ((long)(g * D_ + d0 + j)) * D_ + c * 8);
    *(uint4*)(wlds + (gj * 160 + (c ^ (j & 7))) * 8) = v;
  }
  // zero own tile of h16[0] (plain stores; flushed by the initial release fence)
#pragma unroll
  for (int i = 0; i < 4; ++i) h16[(wr0 + fq * 4 + i) * D_ + mycol] = (f16)0.f;

  float bh0 = bhh[0 * D_ + mycol];
  float bh1 = bhh[1 * D_ + mycol];
  float bh2 = bhh[2 * D_ + mycol];
  float hreg[4] = {0.f, 0.f, 0.f, 0.f};
  f16 xg0[4], xg1[4], xg2[4];

  auto prefetch_x = [&](int tt) {
    const f16* xs = xproj + (((long)tt * 80 + cg) * 3) * 2048 + fr;
#pragma unroll
    for (int i = 0; i < 4; ++i) {
      int b = wr0 + fq * 4 + i;
      xg0[i] = xs[0 * 2048 + b * 16];
      xg1[i] = xs[1 * 2048 + b * 16];
      xg2[i] = xs[2 * 2048 + b * 16];
    }
  };
  auto poll = [&](unsigned target) {
    unsigned it = 0;
    while (__hip_atomic_load(cnt, __ATOMIC_RELAXED, __HIP_MEMORY_SCOPE_AGENT) < target) {
      __builtin_amdgcn_s_sleep(2);
      if (++it > 1000000u) {  // paranoia: RMW reads the coherent point
        if (__hip_atomic_fetch_add(cnt, 0u, __ATOMIC_RELAXED, __HIP_MEMORY_SCOPE_AGENT) >= target)
          break;
      }
    }
  };

  prefetch_x(0);

  // initial barrier: h16[0] zeros visible to the whole rowgroup
  __syncthreads();
  if (tid == 0) {
    __builtin_amdgcn_fence(__ATOMIC_RELEASE, "agent");  // wbl2: flush h zeros to LLC
    __hip_atomic_fetch_add(cnt, 1u, __ATOMIC_RELAXED, __HIP_MEMORY_SCOPE_AGENT);
    poll(80u);
    __builtin_amdgcn_fence(__ATOMIC_ACQUIRE, "agent");  // inv: drop stale L1/L2
  }
  __syncthreads();

  int cur = 0;
  unsigned tgt = 160u;
  for (int t = 0; t < T_; ++t) {
    const f16* hc = h16 + cur * (B_ * D_);
    const f16* arow = hc + (wr0 + fr) * (long)D_ + fq * 8;
    f32x4 acc0 = {}, acc1 = {}, acc2 = {};
#pragma unroll 20
    for (int kb = 0; kb < 40; ++kb) {
      f16x8 a = *(const f16x8*)(arow + kb * 32);   // plain cached load (L2-shared per XCD)
      int cs = (kb * 4 + fq) ^ (fr & 7);
      f16x8 b0 = *(const f16x8*)(wlds + ((0 * 16 + fr) * 160 + cs) * 8);
      f16x8 b1 = *(const f16x8*)(wlds + ((1 * 16 + fr) * 160 + cs) * 8);
      f16x8 b2 = *(const f16x8*)(wlds + ((2 * 16 + fr) * 160 + cs) * 8);
      acc0 = __builtin_amdgcn_mfma_f32_16x16x32_f16(a, b0, acc0, 0, 0, 0);
      acc1 = __builtin_amdgcn_mfma_f32_16x16x32_f16(a, b1, acc1, 0, 0, 0);
      acc2 = __builtin_amdgcn_mfma_f32_16x16x32_f16(a, b2, acc2, 0, 0, 0);
    }
    // gates (xg prefetched last iteration)
    float hnew[4];
#pragma unroll
    for (int i = 0; i < 4; ++i) {
      float gr = (float)xg0[i], gz = (float)xg1[i], gn = (float)xg2[i];
      float r = 1.f / (1.f + __expf(-(gr + acc0[i] + bh0)));
      float z = 1.f / (1.f + __expf(-(gz + acc1[i] + bh1)));
      float pn = gn + r * (acc2[i] + bh2);
      pn = fminf(fmaxf(pn, -30.f), 30.f);
      float e = __expf(-2.f * pn);
      float n = (1.f - e) / (1.f + e);
      hnew[i] = (1.f - z) * n + z * hreg[i];
      hreg[i] = hnew[i];
    }
    if (t == T_ - 1) break;  // last h goes to h32 only
    f16* hn = h16 + (cur ^ 1) * (B_ * D_);
#pragma unroll
    for (int i = 0; i < 4; ++i) hn[(wr0 + fq * 4 + i) * D_ + mycol] = (f16)hnew[i];

    __syncthreads();  // drains all waves' h stores to L2
    if (tid == 0) {
      __builtin_amdgcn_fence(__ATOMIC_RELEASE, "agent");  // wbl2 -> LLC
      __hip_atomic_fetch_add(cnt, 1u, __ATOMIC_RELAXED, __HIP_MEMORY_SCOPE_AGENT);
    }
    prefetch_x(t + 1);  // hide HBM latency behind the barrier wait
    if (tid == 0) {
      poll(tgt);
      __builtin_amdgcn_fence(__ATOMIC_ACQUIRE, "agent");  // inv stale h lines
    }
    __syncthreads();
    tgt += 80u;
    cur ^= 1;
  }
  // final h in fp32 for the scores kernel (kernel-end flush covers visibility)
#pragma unroll
  for (int i = 0; i < 4; ++i) h32[(wr0 + fq * 4 + i) * D_ + mycol] = hreg[i];
}

// ---------------- scores: out[b][c] = sum_d h[b][d]*cand[b][c][d] (fp32) ----------------
__global__ __launch_bounds__(256) void k_scores(const float* __restrict__ h32,
                                                const float* __restrict__ cand,
                                                float* __restrict__ out) {
  int gw = blockIdx.x * 4 + (threadIdx.x >> 6);
  int l = threadIdx.x & 63;
  int b = gw / C_, c = gw % C_;
  const float* hp = h32 + (long)b * D_;
  const float* cp = cand + ((long)b * C_ + c) * D_;
  float s = 0.f;
#pragma unroll
  for (int q = 0; q < 5; ++q) {
    int d = q * 256 + l * 4;
    float4 hv = *(const float4*)(hp + d);
    float4 cv = *(const float4*)(cp + d);
    s += hv.x * cv.x + hv.y * cv.y + hv.z * cv.z + hv.w * cv.w;
  }
#pragma unroll
  for (int off = 32; off > 0; off >>= 1) s += __shfl_down(s, off);
  if (l == 0) out[(long)b * C_ + c] = s;
}

extern "C" void kernel_launch(void* const* d_in, const int* in_sizes, int n_in, void* d_out,
                              int out_size, void* d_ws, size_t ws_size, hipStream_t stream) {
  const float* seq = (const float*)d_in[0];
  const float* cand = (const float*)d_in[1];
  const float* wih = (const float*)d_in[2];
  const float* whh = (const float*)d_in[3];
  const float* bih = (const float*)d_in[4];
  const float* bhh = (const float*)d_in[5];
  char* ws = (char*)d_ws;
  f16* seqb = (f16*)(ws + O_SEQB);
  f16* wih16 = (f16*)(ws + O_WIH);
  f16* whh16 = (f16*)(ws + O_WHH);
  f16* xp = (f16*)(ws + O_XP);
  f16* h16 = (f16*)(ws + O_H16);
  float* h32 = (float*)(ws + O_H32);
  unsigned* bar = (unsigned*)(ws + O_BAR);

  k_convert<<<2048, 256, 0, stream>>>(seq, wih, whh, seqb, wih16, whh16, bar);
  k_xproj<<<7680, 256, 0, stream>>>(seqb, wih16, bih, xp);
  k_scan<<<160, 256, 0, stream>>>(whh16, xp, bhh, h16, h32, bar);
  k_scores<<<3200, 256, 0, stream>>>(h32, cand, (float*)d_out);
}

// Round 4
// 2972.624 us; speedup vs baseline: 1.3998x; 1.3998x over previous
//
#include <hip/hip_runtime.h>
#include <hip/hip_bf16.h>

typedef _Float16 f16;
typedef _Float16 f16x8 __attribute__((ext_vector_type(8)));
typedef float f32x4 __attribute__((ext_vector_type(4)));

#define B_ 128
#define T_ 256
#define D_ 1280
#define G3_ 3840
#define C_ 100
#define TB_ 32768  /* T_*B_ */
#define NBUF 16    /* rotating h buffers */

// ---- workspace layout (bytes) ----
// h buffers overlap the seqb region: seqb is consumed by k_xproj before k_scan runs
// (stream-ordered within each replay; k_convert rewrites seqb every replay).
#define O_H16  0ull                 // f16 [NBUF][B_][D_]  (5 MB, inside seqb region)
#define O_SEQB 0ull                 // f16 [TB_][D_]   (row = t*128+b)
#define O_WIH  83886080ull          // f16 [G3_][D_]
#define O_WHH  93716480ull          // f16 [G3_][D_]
#define O_XP   103546880ull         // f16 [T_][80][3][128][16] compact slabs
#define O_H32  355860480ull         // f32 [B_][D_]
#define O_BAR  356515840ull         // unsigned counters (2 rowgroups, 64B apart)

// ---------------- conversion / init ----------------
__global__ void k_convert(const float* __restrict__ seq, const float* __restrict__ wih,
                          const float* __restrict__ whh, f16* __restrict__ seqb,
                          f16* __restrict__ wih16, f16* __restrict__ whh16,
                          unsigned* __restrict__ bar) {
  if (blockIdx.x == 0 && threadIdx.x < 32)
    __hip_atomic_store(bar + threadIdx.x, 0u, __ATOMIC_RELAXED, __HIP_MEMORY_SCOPE_AGENT);
  const long NSEQ = (long)TB_ * (D_ / 8);
  const long NW = (long)G3_ * (D_ / 8);
  const long total = NSEQ + 2 * NW;
  for (long i = (long)blockIdx.x * blockDim.x + threadIdx.x; i < total;
       i += (long)gridDim.x * blockDim.x) {
    const float* src;
    f16* dst;
    if (i < NSEQ) {
      long row = i / (D_ / 8), c = i % (D_ / 8);
      long t = row >> 7, b = row & 127;
      src = seq + ((b * T_ + t) * (long)D_ + c * 8);
      dst = seqb + (row * (long)D_ + c * 8);
    } else if (i < NSEQ + NW) {
      long j = i - NSEQ;
      src = wih + j * 8;
      dst = wih16 + j * 8;
    } else {
      long j = i - NSEQ - NW;
      src = whh + j * 8;
      dst = whh16 + j * 8;
    }
    float4 a = *(const float4*)src, b4 = *(const float4*)(src + 4);
    f16x8 o;
    o[0] = (f16)a.x; o[1] = (f16)a.y; o[2] = (f16)a.z; o[3] = (f16)a.w;
    o[4] = (f16)b4.x; o[5] = (f16)b4.y; o[6] = (f16)b4.z; o[7] = (f16)b4.w;
    *(f16x8*)dst = o;
  }
}

// ---------------- x_proj GEMM -> compact slab layout [t][cg][g][b][c16] ----------------
__device__ __forceinline__ void gl_lds16(const f16* g, f16* lds) {
  __builtin_amdgcn_global_load_lds((const __attribute__((address_space(1))) void*)g,
                                   (__attribute__((address_space(3))) void*)lds, 16, 0, 0);
}

__global__ __launch_bounds__(256) void k_xproj(const f16* __restrict__ A, const f16* __restrict__ Bw,
                                               const float* __restrict__ bih, f16* __restrict__ Cout) {
  __shared__ f16 Alds[128 * 32];
  __shared__ f16 Blds[128 * 32];
  int bid = blockIdx.x;
  int sb = bid / 240;
  int wi = bid % 240;
  int bm = sb * 8 + (wi & 7);
  int bn = wi >> 3;
  long brow = (long)bm * 128;
  int bcol = bn * 128;
  int tid = threadIdx.x, w = tid >> 6, l = tid & 63;
  int wm = w & 1, wn = w >> 1;

  f32x4 acc[4][4] = {};

  int sr = w * 32 + (l >> 2);
  int sc = (l & 3) * 8;
  const f16* gA = A + (brow + sr) * (long)D_ + sc;
  const f16* gB = Bw + (long)(bcol + sr) * D_ + sc;
  f16* lAw = Alds + (w * 32) * 32;
  f16* lBw = Blds + (w * 32) * 32;

  int fr = l & 15, fc = (l >> 4) * 8;

  for (int kb = 0; kb < 40; ++kb) {
    const f16* a0 = gA + kb * 32;
    const f16* b0 = gB + kb * 32;
    gl_lds16(a0, lAw);
    gl_lds16(a0 + 16 * D_, lAw + 16 * 32);
    gl_lds16(b0, lBw);
    gl_lds16(b0 + 16 * D_, lBw + 16 * 32);
    __syncthreads();
    f16x8 af[4], bf[4];
#pragma unroll
    for (int mt = 0; mt < 4; ++mt) af[mt] = *(const f16x8*)(Alds + (wm * 64 + mt * 16 + fr) * 32 + fc);
#pragma unroll
    for (int nt = 0; nt < 4; ++nt) bf[nt] = *(const f16x8*)(Blds + (wn * 64 + nt * 16 + fr) * 32 + fc);
#pragma unroll
    for (int mt = 0; mt < 4; ++mt)
#pragma unroll
      for (int nt = 0; nt < 4; ++nt)
        acc[mt][nt] = __builtin_amdgcn_mfma_f32_16x16x32_f16(af[mt], bf[nt], acc[mt][nt], 0, 0, 0);
    __syncthreads();
  }
  // epilogue: add b_ih, store f16 into compact slab layout (t = bm).
#pragma unroll
  for (int nt = 0; nt < 4; ++nt) {
    int col = bcol + wn * 64 + nt * 16 + fr;
    int g = col / D_;
    int dcol = col - g * D_;
    int cg = dcol >> 4, c16 = dcol & 15;
    float bv = bih[col];
    f16* base = Cout + (((long)bm * 80 + cg) * 3 + g) * 2048 + c16;
#pragma unroll
    for (int mt = 0; mt < 4; ++mt) {
#pragma unroll
      for (int i = 0; i < 4; ++i) {
        int b = wm * 64 + mt * 16 + (l >> 4) * 4 + i;
        base[b * 16] = (f16)(acc[mt][nt][i] + bv);
      }
    }
  }
}

// ---------------- GRU scan: persistent, 160 blocks ----------------
// XCD-pure mapping: rg = (wg&7)>>2 so all 20 blocks on an XCD share one rowgroup slice.
// h stores: sc1 write-through (LLC). h loads: plain cached (L2-shared per XCD).
// Staleness handled by NBUF rotating buffers + acquire fence every NBUF steps
// (+ one at kernel start for cross-replay staleness).
__global__ __launch_bounds__(256, 1) void k_scan(const f16* __restrict__ whh16,
                                                 const f16* __restrict__ xproj,
                                                 const float* __restrict__ bhh,
                                                 f16* __restrict__ h16, float* __restrict__ h32,
                                                 unsigned* __restrict__ bar) {
  __shared__ f16 wlds[3 * 16 * D_];  // 120 KB, wave-linear chunk layout
  int wg = blockIdx.x;
  int rg = (wg & 7) >> 2;                    // XCD-pure rowgroup
  int cg = (wg >> 3) * 4 + (wg & 3);         // 0..79
  int r0 = rg * 64, d0 = cg * 16;
  int tid = threadIdx.x, w = tid >> 6, l = tid & 63;
  int wr0 = r0 + w * 16;
  int fr = l & 15, fq = l >> 4;
  int mycol = d0 + fr;
  unsigned* cnt = bar + rg * 16;

  // load W_hh chunk into LDS, wave-linear layout:
  // chunk(row j, K-chunk c8=kb*4+fq) -> index ((kb*3+g)*4+fq)*16 + j
  for (int q = tid; q < 3 * 16 * 160; q += 256) {
    int rowg = q / 160, c8 = q % 160;
    int g = rowg >> 4, j = rowg & 15;
    int kb = c8 >> 2, kq = c8 & 3;
    uint4 v = *(const uint4*)(whh16 + ((long)(g * D_ + d0 + j)) * D_ + c8 * 8);
    *(uint4*)(wlds + (((kb * 3 + g) * 4 + kq) * 16 + j) * 8) = v;
  }
  // zero own tile of h buffer 0 via sc1 write-through (pairs of cols)
#pragma unroll
  for (int i = 0; i < 4; ++i) {
    if ((fr & 1) == 0) {
      unsigned* p = (unsigned*)(h16 + (wr0 + fq * 4 + i) * D_ + mycol);
      __hip_atomic_store(p, 0u, __ATOMIC_RELAXED, __HIP_MEMORY_SCOPE_AGENT);
    }
  }

  float bh0 = bhh[0 * D_ + mycol];
  float bh1 = bhh[1 * D_ + mycol];
  float bh2 = bhh[2 * D_ + mycol];
  float hreg[4] = {0.f, 0.f, 0.f, 0.f};
  f16 xg0[4], xg1[4], xg2[4];

  auto prefetch_x = [&](int tt) {
    const f16* xs = xproj + (((long)tt * 80 + cg) * 3) * 2048 + fr;
#pragma unroll
    for (int i = 0; i < 4; ++i) {
      int b = wr0 + fq * 4 + i;
      xg0[i] = xs[0 * 2048 + b * 16];
      xg1[i] = xs[1 * 2048 + b * 16];
      xg2[i] = xs[2 * 2048 + b * 16];
    }
  };
  auto poll = [&](unsigned target) {
    unsigned it = 0;
    while (__hip_atomic_load(cnt, __ATOMIC_RELAXED, __HIP_MEMORY_SCOPE_AGENT) < target) {
      __builtin_amdgcn_s_sleep(2);
      if (++it > 1000000u) {
        if (__hip_atomic_fetch_add(cnt, 0u, __ATOMIC_RELAXED, __HIP_MEMORY_SCOPE_AGENT) >= target)
          break;
      }
    }
  };

  prefetch_x(0);

  // initial barrier + cross-replay cache scrub (one inv per kernel, not per step)
  __syncthreads();
  if (tid == 0) {
    __hip_atomic_fetch_add(cnt, 1u, __ATOMIC_RELAXED, __HIP_MEMORY_SCOPE_AGENT);
    poll(80u);
    __builtin_amdgcn_fence(__ATOMIC_ACQUIRE, "agent");  // drop stale L1/L2 from prior replay
  }
  __syncthreads();

  unsigned tgt = 160u;
  for (int t = 0; t < T_; ++t) {
    const f16* hc = h16 + (t & (NBUF - 1)) * (B_ * D_);
    const f16* arow = hc + (wr0 + fr) * (long)D_ + fq * 8;
    f32x4 acc0 = {}, acc1 = {}, acc2 = {};
#pragma unroll 10
    for (int kb = 0; kb < 40; ++kb) {
      f16x8 a = *(const f16x8*)(arow + kb * 32);  // plain cached load, L2-shared per XCD
      const f16* wb = wlds + (((kb * 3) * 4 + fq) * 16 + fr) * 8;
      f16x8 b0 = *(const f16x8*)(wb);
      f16x8 b1 = *(const f16x8*)(wb + 512);
      f16x8 b2 = *(const f16x8*)(wb + 1024);
      acc0 = __builtin_amdgcn_mfma_f32_16x16x32_f16(a, b0, acc0, 0, 0, 0);
      acc1 = __builtin_amdgcn_mfma_f32_16x16x32_f16(a, b1, acc1, 0, 0, 0);
      acc2 = __builtin_amdgcn_mfma_f32_16x16x32_f16(a, b2, acc2, 0, 0, 0);
    }
    float hnew[4];
#pragma unroll
    for (int i = 0; i < 4; ++i) {
      float gr = (float)xg0[i], gz = (float)xg1[i], gn = (float)xg2[i];
      float r = 1.f / (1.f + __expf(-(gr + acc0[i] + bh0)));
      float z = 1.f / (1.f + __expf(-(gz + acc1[i] + bh1)));
      float pn = gn + r * (acc2[i] + bh2);
      pn = fminf(fmaxf(pn, -30.f), 30.f);
      float e = __expf(-2.f * pn);
      float n = (1.f - e) / (1.f + e);
      hnew[i] = (1.f - z) * n + z * hreg[i];
      hreg[i] = hnew[i];
    }
    if (t == T_ - 1) break;
    f16* hn = h16 + ((t + 1) & (NBUF - 1)) * (B_ * D_);
#pragma unroll
    for (int i = 0; i < 4; ++i) {
      int row = wr0 + fq * 4 + i;
      unsigned short bits = __builtin_bit_cast(unsigned short, (f16)hnew[i]);
      unsigned other = (unsigned)__shfl_xor((int)bits, 1);
      if ((fr & 1) == 0) {
        unsigned val = (unsigned)bits | (other << 16);
        unsigned* p = (unsigned*)(hn + row * D_ + mycol);
        __hip_atomic_store(p, val, __ATOMIC_RELAXED, __HIP_MEMORY_SCOPE_AGENT);
      }
    }
    __syncthreads();  // drains all waves' sc1 stores (vmcnt) before signal
    if (tid == 0)
      __hip_atomic_fetch_add(cnt, 1u, __ATOMIC_RELAXED, __HIP_MEMORY_SCOPE_AGENT);
    prefetch_x(t + 1);  // in flight during the poll
    if (tid == 0) {
      poll(tgt);
      if (((t + 1) & (NBUF - 1)) == 0)
        __builtin_amdgcn_fence(__ATOMIC_ACQUIRE, "agent");  // periodic stale-line scrub
    }
    __syncthreads();
    tgt += 80u;
  }
  // final h in fp32 for the scores kernel (kernel-end flush covers visibility)
#pragma unroll
  for (int i = 0; i < 4; ++i) h32[(wr0 + fq * 4 + i) * D_ + mycol] = hreg[i];
}

// ---------------- scores: out[b][c] = sum_d h[b][d]*cand[b][c][d] (fp32) ----------------
__global__ __launch_bounds__(256) void k_scores(const float* __restrict__ h32,
                                                const float* __restrict__ cand,
                                                float* __restrict__ out) {
  int gw = blockIdx.x * 4 + (threadIdx.x >> 6);
  int l = threadIdx.x & 63;
  int b = gw / C_, c = gw % C_;
  const float* hp = h32 + (long)b * D_;
  const float* cp = cand + ((long)b * C_ + c) * D_;
  float s = 0.f;
#pragma unroll
  for (int q = 0; q < 5; ++q) {
    int d = q * 256 + l * 4;
    float4 hv = *(const float4*)(hp + d);
    float4 cv = *(const float4*)(cp + d);
    s += hv.x * cv.x + hv.y * cv.y + hv.z * cv.z + hv.w * cv.w;
  }
#pragma unroll
  for (int off = 32; off > 0; off >>= 1) s += __shfl_down(s, off);
  if (l == 0) out[(long)b * C_ + c] = s;
}

extern "C" void kernel_launch(void* const* d_in, const int* in_sizes, int n_in, void* d_out,
                              int out_size, void* d_ws, size_t ws_size, hipStream_t stream) {
  const float* seq = (const float*)d_in[0];
  const float* cand = (const float*)d_in[1];
  const float* wih = (const float*)d_in[2];
  const float* whh = (const float*)d_in[3];
  const float* bih = (const float*)d_in[4];
  const float* bhh = (const float*)d_in[5];
  char* ws = (char*)d_ws;
  f16* seqb = (f16*)(ws + O_SEQB);
  f16* wih16 = (f16*)(ws + O_WIH);
  f16* whh16 = (f16*)(ws + O_WHH);
  f16* xp = (f16*)(ws + O_XP);
  f16* h16 = (f16*)(ws + O_H16);  // rotating buffers, overlapping seqb (dead by then)
  float* h32 = (float*)(ws + O_H32);
  unsigned* bar = (unsigned*)(ws + O_BAR);

  k_convert<<<2048, 256, 0, stream>>>(seq, wih, whh, seqb, wih16, whh16, bar);
  k_xproj<<<7680, 256, 0, stream>>>(seqb, wih16, bih, xp);
  k_scan<<<160, 256, 0, stream>>>(whh16, xp, bhh, h16, h32, bar);
  k_scores<<<3200, 256, 0, stream>>>(h32, cand, (float*)d_out);
}

// Round 6
// 2276.011 us; speedup vs baseline: 1.8282x; 1.3061x over previous
//
#include <hip/hip_runtime.h>
#include <hip/hip_bf16.h>

typedef _Float16 f16;
typedef _Float16 f16x8 __attribute__((ext_vector_type(8)));
typedef float f32x4 __attribute__((ext_vector_type(4)));

#define B_ 128
#define T_ 256
#define D_ 1280
#define G3_ 3840
#define C_ 100
#define TB_ 32768  /* T_*B_ */
#define NBUF 16    /* rotating h buffers */

// ---- workspace layout (bytes) ----
// h buffers overlap the seqb region: seqb is consumed by k_xproj before k_scan runs
// (stream-ordered within each replay; k_convert rewrites seqb every replay).
#define O_H16  0ull                 // f16 [NBUF][B_][D_]  (5 MB, inside seqb region)
#define O_SEQB 0ull                 // f16 [TB_][D_]   (row = t*128+b)
#define O_WIH  83886080ull          // f16 [G3_][D_]
#define O_WHH  93716480ull          // f16 [G3_][D_]
#define O_XP   103546880ull         // f16 [T_][80][3][128][16] compact slabs
#define O_H32  355860480ull         // f32 [B_][D_]
#define O_BAR  356515840ull         // u32 counters: (rg*16+shard)*32 stride (128B), 32 shards

// ---------------- conversion / init ----------------
__global__ void k_convert(const float* __restrict__ seq, const float* __restrict__ wih,
                          const float* __restrict__ whh, f16* __restrict__ seqb,
                          f16* __restrict__ wih16, f16* __restrict__ whh16,
                          unsigned* __restrict__ bar) {
  if (blockIdx.x == 0) {
    for (int j = threadIdx.x; j < 1024; j += 256)
      __hip_atomic_store(bar + j, 0u, __ATOMIC_RELAXED, __HIP_MEMORY_SCOPE_AGENT);
  }
  const long NSEQ = (long)TB_ * (D_ / 8);
  const long NW = (long)G3_ * (D_ / 8);
  const long total = NSEQ + 2 * NW;
  for (long i = (long)blockIdx.x * blockDim.x + threadIdx.x; i < total;
       i += (long)gridDim.x * blockDim.x) {
    const float* src;
    f16* dst;
    if (i < NSEQ) {
      long row = i / (D_ / 8), c = i % (D_ / 8);
      long t = row >> 7, b = row & 127;
      src = seq + ((b * T_ + t) * (long)D_ + c * 8);
      dst = seqb + (row * (long)D_ + c * 8);
    } else if (i < NSEQ + NW) {
      long j = i - NSEQ;
      src = wih + j * 8;
      dst = wih16 + j * 8;
    } else {
      long j = i - NSEQ - NW;
      src = whh + j * 8;
      dst = whh16 + j * 8;
    }
    float4 a = *(const float4*)src, b4 = *(const float4*)(src + 4);
    f16x8 o;
    o[0] = (f16)a.x; o[1] = (f16)a.y; o[2] = (f16)a.z; o[3] = (f16)a.w;
    o[4] = (f16)b4.x; o[5] = (f16)b4.y; o[6] = (f16)b4.z; o[7] = (f16)b4.w;
    *(f16x8*)dst = o;
  }
}

// ---------------- x_proj GEMM -> compact slab layout [t][cg][g][b][c16] ----------------
__device__ __forceinline__ void gl_lds16(const f16* g, f16* lds) {
  __builtin_amdgcn_global_load_lds((const __attribute__((address_space(1))) void*)g,
                                   (__attribute__((address_space(3))) void*)lds, 16, 0, 0);
}

__global__ __launch_bounds__(256) void k_xproj(const f16* __restrict__ A, const f16* __restrict__ Bw,
                                               const float* __restrict__ bih, f16* __restrict__ Cout) {
  __shared__ f16 Alds[128 * 32];
  __shared__ f16 Blds[128 * 32];
  int bid = blockIdx.x;
  int sb = bid / 240;
  int wi = bid % 240;
  int bm = sb * 8 + (wi & 7);
  int bn = wi >> 3;
  long brow = (long)bm * 128;
  int bcol = bn * 128;
  int tid = threadIdx.x, w = tid >> 6, l = tid & 63;
  int wm = w & 1, wn = w >> 1;

  f32x4 acc[4][4] = {};

  int sr = w * 32 + (l >> 2);
  int sc = (l & 3) * 8;
  const f16* gA = A + (brow + sr) * (long)D_ + sc;
  const f16* gB = Bw + (long)(bcol + sr) * D_ + sc;
  f16* lAw = Alds + (w * 32) * 32;
  f16* lBw = Blds + (w * 32) * 32;

  int fr = l & 15, fc = (l >> 4) * 8;

  for (int kb = 0; kb < 40; ++kb) {
    const f16* a0 = gA + kb * 32;
    const f16* b0 = gB + kb * 32;
    gl_lds16(a0, lAw);
    gl_lds16(a0 + 16 * D_, lAw + 16 * 32);
    gl_lds16(b0, lBw);
    gl_lds16(b0 + 16 * D_, lBw + 16 * 32);
    __syncthreads();
    f16x8 af[4], bf[4];
#pragma unroll
    for (int mt = 0; mt < 4; ++mt) af[mt] = *(const f16x8*)(Alds + (wm * 64 + mt * 16 + fr) * 32 + fc);
#pragma unroll
    for (int nt = 0; nt < 4; ++nt) bf[nt] = *(const f16x8*)(Blds + (wn * 64 + nt * 16 + fr) * 32 + fc);
#pragma unroll
    for (int mt = 0; mt < 4; ++mt)
#pragma unroll
      for (int nt = 0; nt < 4; ++nt)
        acc[mt][nt] = __builtin_amdgcn_mfma_f32_16x16x32_f16(af[mt], bf[nt], acc[mt][nt], 0, 0, 0);
    __syncthreads();
  }
  // epilogue: add b_ih, store f16 into compact slab layout (t = bm).
#pragma unroll
  for (int nt = 0; nt < 4; ++nt) {
    int col = bcol + wn * 64 + nt * 16 + fr;
    int g = col / D_;
    int dcol = col - g * D_;
    int cg = dcol >> 4, c16 = dcol & 15;
    float bv = bih[col];
    f16* base = Cout + (((long)bm * 80 + cg) * 3 + g) * 2048 + c16;
#pragma unroll
    for (int mt = 0; mt < 4; ++mt) {
#pragma unroll
      for (int i = 0; i < 4; ++i) {
        int b = wm * 64 + mt * 16 + (l >> 4) * 4 + i;
        base[b * 16] = (f16)(acc[mt][nt][i] + bv);
      }
    }
  }
}

// ---------------- GRU scan: persistent, 160 blocks ----------------
// XCD-pure mapping: rg = (wg&7)>>2 -> all 20 blocks on an XCD share one rowgroup slice.
// h stores: sc1 write-through (LLC). h loads: plain cached (L2-shared per XCD).
// Staleness: NBUF rotating buffers + acquire fence every NBUF steps (+1 at kernel start).
// Barrier: 16 sharded counters per rowgroup, EXACTLY 5 arrivals each per step
// (shard = ((q&3)<<2)|(wg&3)); wave-0 lanes 0..15 poll the 16 lines in parallel.
__global__ __launch_bounds__(256, 1) void k_scan(const f16* __restrict__ whh16,
                                                 const f16* __restrict__ xproj,
                                                 const float* __restrict__ bhh,
                                                 f16* __restrict__ h16, float* __restrict__ h32,
                                                 unsigned* __restrict__ bar) {
  __shared__ f16 wlds[3 * 16 * D_];  // 120 KB, wave-linear chunk layout
  int wg = blockIdx.x;
  int rg = (wg & 7) >> 2;                    // XCD-pure rowgroup
  int q = wg >> 3;                           // 0..19
  int cg = q * 4 + (wg & 3);                 // 0..79
  int r0 = rg * 64, d0 = cg * 16;
  int tid = threadIdx.x, w = tid >> 6, l = tid & 63;
  int wr0 = r0 + w * 16;
  int fr = l & 15, fq = l >> 4;
  int mycol = d0 + fr;
  int shard = ((q & 3) << 2) | (wg & 3);     // 16 shards/rowgroup, 5 blocks each
  unsigned* mycnt = bar + (rg * 16 + shard) * 32;  // 128B-spaced lines
  int koff = (q & 3) * 10;                   // K-loop start rotation (4 phases)

  // load W_hh chunk into LDS, wave-linear layout:
  // chunk(row j, K-chunk c8=kb*4+kq) -> index ((kb*3+g)*4+kq)*16 + j
  for (int qq = tid; qq < 3 * 16 * 160; qq += 256) {
    int rowg = qq / 160, c8 = qq % 160;
    int g = rowg >> 4, j = rowg & 15;
    int kb = c8 >> 2, kq = c8 & 3;
    uint4 v = *(const uint4*)(whh16 + ((long)(g * D_ + d0 + j)) * D_ + c8 * 8);
    *(uint4*)(wlds + (((kb * 3 + g) * 4 + kq) * 16 + j) * 8) = v;
  }
  // zero own tile of h buffer 0 via sc1 write-through (pairs of cols)
#pragma unroll
  for (int i = 0; i < 4; ++i) {
    if ((fr & 1) == 0) {
      unsigned* p = (unsigned*)(h16 + (wr0 + fq * 4 + i) * D_ + mycol);
      __hip_atomic_store(p, 0u, __ATOMIC_RELAXED, __HIP_MEMORY_SCOPE_AGENT);
    }
  }

  float bh0 = bhh[0 * D_ + mycol];
  float bh1 = bhh[1 * D_ + mycol];
  float bh2 = bhh[2 * D_ + mycol];
  float hreg[4] = {0.f, 0.f, 0.f, 0.f};
  f16 xg0[4], xg1[4], xg2[4];

  auto prefetch_x = [&](int tt) {
    const f16* xs = xproj + (((long)tt * 80 + cg) * 3) * 2048 + fr;
#pragma unroll
    for (int i = 0; i < 4; ++i) {
      int b = wr0 + fq * 4 + i;
      xg0[i] = xs[0 * 2048 + b * 16];
      xg1[i] = xs[1 * 2048 + b * 16];
      xg2[i] = xs[2 * 2048 + b * 16];
    }
  };
  // wave-0 poll: lanes 0..15 each watch one shard line (parallel LLC loads)
  auto poll16 = [&](unsigned target) {
    unsigned it = 0;
    for (;;) {
      unsigned v = target;
      if (l < 16)
        v = __hip_atomic_load(bar + (rg * 16 + l) * 32, __ATOMIC_RELAXED, __HIP_MEMORY_SCOPE_AGENT);
      if (__all(v >= target)) break;
      __builtin_amdgcn_s_sleep(1);
      if (++it > 500000u) {  // paranoia: RMW reads the coherent point
        if (l < 16)
          v = __hip_atomic_fetch_add(bar + (rg * 16 + l) * 32, 0u, __ATOMIC_RELAXED,
                                     __HIP_MEMORY_SCOPE_AGENT);
        if (__all(v >= target)) break;
        it = 0;
      }
    }
  };

  prefetch_x(0);

  // initial barrier + cross-replay cache scrub (one inv per kernel, not per step)
  __syncthreads();
  if (tid == 0)
    __hip_atomic_fetch_add(mycnt, 1u, __ATOMIC_RELAXED, __HIP_MEMORY_SCOPE_AGENT);
  if (tid < 64) {
    poll16(5u);
    if (tid == 0) __builtin_amdgcn_fence(__ATOMIC_ACQUIRE, "agent");  // drop stale prior-replay lines
  }
  __syncthreads();

  unsigned tgt = 10u;
  for (int t = 0; t < T_; ++t) {
    const f16* hc = h16 + (t & (NBUF - 1)) * (B_ * D_);
    const f16* arow = hc + (wr0 + fr) * (long)D_ + fq * 8;
    f32x4 acc0 = {}, acc1 = {}, acc2 = {};
#pragma unroll 10
    for (int ii = 0; ii < 40; ++ii) {
      int kb = ii + koff;
      kb = (kb >= 40) ? kb - 40 : kb;   // rotated start: blocks fetch disjoint quarters first
      f16x8 a = *(const f16x8*)(arow + kb * 32);  // plain cached load, L2-shared per XCD
      const f16* wb = wlds + kb * 1536 + (fq * 16 + fr) * 8;
      f16x8 b0 = *(const f16x8*)(wb);
      f16x8 b1 = *(const f16x8*)(wb + 512);
      f16x8 b2 = *(const f16x8*)(wb + 1024);
      acc0 = __builtin_amdgcn_mfma_f32_16x16x32_f16(a, b0, acc0, 0, 0, 0);
      acc1 = __builtin_amdgcn_mfma_f32_16x16x32_f16(a, b1, acc1, 0, 0, 0);
      acc2 = __builtin_amdgcn_mfma_f32_16x16x32_f16(a, b2, acc2, 0, 0, 0);
    }
    float hnew[4];
#pragma unroll
    for (int i = 0; i < 4; ++i) {
      float gr = (float)xg0[i], gz = (float)xg1[i], gn = (float)xg2[i];
      float r = 1.f / (1.f + __expf(-(gr + acc0[i] + bh0)));
      float z = 1.f / (1.f + __expf(-(gz + acc1[i] + bh1)));
      float pn = gn + r * (acc2[i] + bh2);
      pn = fminf(fmaxf(pn, -30.f), 30.f);
      float e = __expf(-2.f * pn);
      float n = (1.f - e) / (1.f + e);
      hnew[i] = (1.f - z) * n + z * hreg[i];
      hreg[i] = hnew[i];
    }
    if (t == T_ - 1) break;
    f16* hn = h16 + ((t + 1) & (NBUF - 1)) * (B_ * D_);
#pragma unroll
    for (int i = 0; i < 4; ++i) {
      int row = wr0 + fq * 4 + i;
      unsigned short bits = __builtin_bit_cast(unsigned short, (f16)hnew[i]);
      unsigned other = (unsigned)__shfl_xor((int)bits, 1);
      if ((fr & 1) == 0) {
        unsigned val = (unsigned)bits | (other << 16);
        unsigned* p = (unsigned*)(hn + row * D_ + mycol);
        __hip_atomic_store(p, val, __ATOMIC_RELAXED, __HIP_MEMORY_SCOPE_AGENT);
      }
    }
    __syncthreads();  // drains all waves' sc1 stores (vmcnt) before signal
    if (tid == 0)
      __hip_atomic_fetch_add(mycnt, 1u, __ATOMIC_RELAXED, __HIP_MEMORY_SCOPE_AGENT);
    prefetch_x(t + 1);  // in flight during the poll
    if (tid < 64) {
      poll16(tgt);
      if (tid == 0 && (((t + 1) & (NBUF - 1)) == 0))
        __builtin_amdgcn_fence(__ATOMIC_ACQUIRE, "agent");  // periodic stale-line scrub
    }
    __syncthreads();
    tgt += 5u;
  }
  // final h in fp32 for the scores kernel (kernel-end flush covers visibility)
#pragma unroll
  for (int i = 0; i < 4; ++i) h32[(wr0 + fq * 4 + i) * D_ + mycol] = hreg[i];
}

// ---------------- scores: out[b][c] = sum_d h[b][d]*cand[b][c][d] (fp32) ----------------
__global__ __launch_bounds__(256) void k_scores(const float* __restrict__ h32,
                                                const float* __restrict__ cand,
                                                float* __restrict__ out) {
  int gw = blockIdx.x * 4 + (threadIdx.x >> 6);
  int l = threadIdx.x & 63;
  int b = gw / C_, c = gw % C_;
  const float* hp = h32 + (long)b * D_;
  const float* cp = cand + ((long)b * C_ + c) * D_;
  float s = 0.f;
#pragma unroll
  for (int q = 0; q < 5; ++q) {
    int d = q * 256 + l * 4;
    float4 hv = *(const float4*)(hp + d);
    float4 cv = *(const float4*)(cp + d);
    s += hv.x * cv.x + hv.y * cv.y + hv.z * cv.z + hv.w * cv.w;
  }
#pragma unroll
  for (int off = 32; off > 0; off >>= 1) s += __shfl_down(s, off);
  if (l == 0) out[(long)b * C_ + c] = s;
}

extern "C" void kernel_launch(void* const* d_in, const int* in_sizes, int n_in, void* d_out,
                              int out_size, void* d_ws, size_t ws_size, hipStream_t stream) {
  const float* seq = (const float*)d_in[0];
  const float* cand = (const float*)d_in[1];
  const float* wih = (const float*)d_in[2];
  const float* whh = (const float*)d_in[3];
  const float* bih = (const float*)d_in[4];
  const float* bhh = (const float*)d_in[5];
  char* ws = (char*)d_ws;
  f16* seqb = (f16*)(ws + O_SEQB);
  f16* wih16 = (f16*)(ws + O_WIH);
  f16* whh16 = (f16*)(ws + O_WHH);
  f16* xp = (f16*)(ws + O_XP);
  f16* h16 = (f16*)(ws + O_H16);  // rotating buffers, overlapping seqb (dead by then)
  float* h32 = (float*)(ws + O_H32);
  unsigned* bar = (unsigned*)(ws + O_BAR);

  k_convert<<<2048, 256, 0, stream>>>(seq, wih, whh, seqb, wih16, whh16, bar);
  k_xproj<<<7680, 256, 0, stream>>>(seqb, wih16, bih, xp);
  k_scan<<<160, 256, 0, stream>>>(whh16, xp, bhh, h16, h32, bar);
  k_scores<<<3200, 256, 0, stream>>>(h32, cand, (float*)d_out);
}